// Round 12
// baseline (130.996 us; speedup 1.0000x reference)
//
#include <hip/hip_runtime.h>

#define BATCH 4096
#define MD 384
#define KW 15
#define LSEQ 28
#define FIN 28
#define NX (BATCH*LSEQ*FIN)
#define NROWS (BATCH*LSEQ)
#define SAMP 3
#define NB 1366          // ceil(4096/3)

// scf slots: 0 s_img, 1 s_w1, 2 s_wc, 3 s_wf, 4 s_lin, 5 s_o1, 6 s_cv, 7 s_o2
// workspace layout (byte offsets, 16B-aligned)
#define B_SCF  0
#define B_LUT1 256
#define B_LUT2 512
#define B_PT0  1024      // 2048 float4
#define B_PT1  33792     // 1366 float2
#define B_PT2  50176     // 1366 float2
#define B_PTL  66560     // 1366 float
#define B_W1B  74752     // MD*32 bf16 = 24576
#define B_WCQ  99328     // MD*16 i8 = 6144
#define B_WFB  105472    // 16*10752 i8 = 172032 (rows 10..15 pad)
#define B_LG   277504    // 40960 float
#define B_XQB  441344    // NROWS*32 bf16 = 7340032

typedef __bf16 bf16x8 __attribute__((ext_vector_type(8)));
typedef float f32x4 __attribute__((ext_vector_type(4)));
typedef int i32x4 __attribute__((ext_vector_type(4)));

#if __has_builtin(__builtin_amdgcn_sdot4)
#define SDOT4(a,b,c) __builtin_amdgcn_sdot4((a),(b),(c),false)
#else
__device__ __forceinline__ int SDOT4(int a,int b,int c){
  c += ((a<<24)>>24)*((b<<24)>>24);
  c += ((a<<16)>>24)*((b<<16)>>24);
  c += ((a<<8)>>24)*((b<<8)>>24);
  c += (a>>24)*(b>>24);
  return c;
}
#endif

#if __has_builtin(__builtin_amdgcn_alignbyte)
#define ALIGNB(hi,lo,s) __builtin_amdgcn_alignbyte((hi),(lo),(s))
#else
#define ALIGNB(hi,lo,s) ((int)(((unsigned)(lo)>>(8*(s)))|((unsigned)(hi)<<(32-8*(s)))))
#endif

__device__ __forceinline__ unsigned short f2bf(float f){
  return (unsigned short)(__float_as_uint(f)>>16);   // exact for small ints
}
__device__ __forceinline__ unsigned lut_bperm(int iw,int lutw){
  int res=__builtin_amdgcn_ds_bpermute(iw,lutw);    // lane = iw>>2
  return ((unsigned)res>>(8*(iw&3)))&0xFFu;
}

__device__ __forceinline__ void blkStore4(float m0,float m1,float m2,float m3,float4* dst){
  #pragma unroll
  for(int off=32;off;off>>=1){
    m0=fmaxf(m0,__shfl_xor(m0,off,64));
    m1=fmaxf(m1,__shfl_xor(m1,off,64));
    m2=fmaxf(m2,__shfl_xor(m2,off,64));
    m3=fmaxf(m3,__shfl_xor(m3,off,64));
  }
  __shared__ float sm[4][4];
  int wid=threadIdx.x>>6;
  if((threadIdx.x&63)==0){sm[wid][0]=m0;sm[wid][1]=m1;sm[wid][2]=m2;sm[wid][3]=m3;}
  __syncthreads();
  if(threadIdx.x==0){
    for(int i=1;i<4;i++){
      m0=fmaxf(m0,sm[i][0]);m1=fmaxf(m1,sm[i][1]);
      m2=fmaxf(m2,sm[i][2]);m3=fmaxf(m3,sm[i][3]);
    }
    *dst=make_float4(m0,m1,m2,m3);
  }
}

__device__ __forceinline__ void blkStoreMM(float mn,float mx,float2* dst){
  #pragma unroll
  for(int off=32;off;off>>=1){
    mn=fminf(mn,__shfl_xor(mn,off,64));
    mx=fmaxf(mx,__shfl_xor(mx,off,64));
  }
  __shared__ float smn[8],smx[8];
  int wid=threadIdx.x>>6, nw=blockDim.x>>6;
  if((threadIdx.x&63)==0){smn[wid]=mn;smx[wid]=mx;}
  __syncthreads();
  if(threadIdx.x==0){
    for(int i=1;i<nw;i++){mn=fminf(mn,smn[i]);mx=fmaxf(mx,smx[i]);}
    *dst=make_float2(mn,mx);
  }
}

// ---------- kernels ----------
__global__ __launch_bounds__(256)
void k_maxabs_in(const float* __restrict__ img,const float* __restrict__ W1,
                 const float* __restrict__ Wc,const float* __restrict__ Wf,
                 float4* __restrict__ pt0){
  float m0=0.f,m1=0.f,m2=0.f,m3=0.f;
  const int N4=NX/4;
  const int NW1=MD*FIN, NWC=MD*KW, NWF=10*MD*LSEQ;
  const int total=N4+NW1+NWC+NWF;
  const float4* img4=(const float4*)img;
  for(int i=blockIdx.x*blockDim.x+threadIdx.x;i<total;i+=gridDim.x*blockDim.x){
    if(i<N4){
      float4 v=img4[i];
      m0=fmaxf(m0,fmaxf(fmaxf(fabsf(v.x),fabsf(v.y)),fmaxf(fabsf(v.z),fabsf(v.w))));
    }
    else if(i<N4+NW1) m1=fmaxf(m1,fabsf(W1[i-N4]));
    else if(i<N4+NW1+NWC) m2=fmaxf(m2,fabsf(Wc[i-N4-NW1]));
    else m3=fmaxf(m3,fabsf(Wf[i-N4-NW1-NWC]));
  }
  blkStore4(m0,m1,m2,m3,&pt0[blockIdx.x]);
}

__global__ __launch_bounds__(256)
void k_red0(const float4* __restrict__ pt,float* __restrict__ scf){
  int t=threadIdx.x;
  float m0=0.f,m1=0.f,m2=0.f,m3=0.f;
  for(int i=t;i<2048;i+=256){
    float4 v=pt[i];
    m0=fmaxf(m0,v.x);m1=fmaxf(m1,v.y);m2=fmaxf(m2,v.z);m3=fmaxf(m3,v.w);
  }
  #pragma unroll
  for(int off=32;off;off>>=1){
    m0=fmaxf(m0,__shfl_xor(m0,off,64));
    m1=fmaxf(m1,__shfl_xor(m1,off,64));
    m2=fmaxf(m2,__shfl_xor(m2,off,64));
    m3=fmaxf(m3,__shfl_xor(m3,off,64));
  }
  __shared__ float sm[4][4];
  int wid=t>>6;
  if((t&63)==0){sm[wid][0]=m0;sm[wid][1]=m1;sm[wid][2]=m2;sm[wid][3]=m3;}
  __syncthreads();
  if(t==0){
    for(int i=1;i<4;i++){
      m0=fmaxf(m0,sm[i][0]);m1=fmaxf(m1,sm[i][1]);
      m2=fmaxf(m2,sm[i][2]);m3=fmaxf(m3,sm[i][3]);
    }
    scf[0]=fmaxf(m0/127.f,1e-8f);
    scf[1]=fmaxf(m1/3.f,1e-8f);
    scf[2]=fmaxf(m2/3.f,1e-8f);
    scf[3]=fmaxf(m3/3.f,1e-8f);
  }
}

__global__ __launch_bounds__(256)
void k_redmm(const float2* __restrict__ pt,int n,float* __restrict__ scf,
             int preIdx,int outIdx,char* __restrict__ lutg){
  int t=threadIdx.x;
  float mn=1e30f,mx=-1e30f;
  for(int i=t;i<n;i+=256){
    float2 v=pt[i];
    mn=fminf(mn,v.x); mx=fmaxf(mx,v.y);
  }
  #pragma unroll
  for(int off=32;off;off>>=1){
    mn=fminf(mn,__shfl_xor(mn,off,64));
    mx=fmaxf(mx,__shfl_xor(mx,off,64));
  }
  __shared__ float smn[4],smx[4];
  __shared__ float bs,bso;
  int wid=t>>6;
  if((t&63)==0){smn[wid]=mn;smx[wid]=mx;}
  __syncthreads();
  if(t==0){
    for(int i=1;i<4;i++){mn=fminf(mn,smn[i]);mx=fmaxf(mx,smx[i]);}
    float ma=fmaxf(fabsf(mn),fabsf(mx));
    float s=fmaxf(ma/127.f,1e-8f);
    float a1=fabsf(fminf(fmaxf(rintf(mn/s),-128.f),127.f)*s);
    float a2=fabsf(fminf(fmaxf(rintf(mx/s),-128.f),127.f)*s);
    float so=fmaxf(tanhf(fmaxf(a1,a2))/127.f,1e-8f);
    scf[preIdx]=s; scf[outIdx]=so;
    bs=s; bso=so;
  }
  __syncthreads();
  float d=(float)(t-128)*bs;
  lutg[t]=(char)(int)fminf(fmaxf(rintf(tanhf(d)/bso),-128.f),127.f);
}

// quantize inputs into code tensors
__global__ __launch_bounds__(256)
void k_prep(const float* __restrict__ img,const float* __restrict__ W1,
            const float* __restrict__ Wc,const float* __restrict__ Wf,
            const float* __restrict__ scf,char* __restrict__ wsb){
  float s_img=scf[0], s_w1=scf[1], s_wc=scf[2], s_wf=scf[3];
  float inv_img=1.f/s_img;
  unsigned short* xqb=(unsigned short*)(wsb+B_XQB);
  unsigned short* w1b=(unsigned short*)(wsb+B_W1B);
  char* wcpk=wsb+B_WCQ;
  char* wfb=wsb+B_WFB;
  const int T0=NROWS*32;
  const int T1=T0+MD*32;
  const int T2=T1+MD*16;
  const int T3=T2+10*10752;
  for(int i=blockIdx.x*blockDim.x+threadIdx.x;i<T3;i+=gridDim.x*blockDim.x){
    if(i<T0){
      int row=i>>5, cc=i&31;
      float q = cc<FIN ? fminf(fmaxf(rintf(img[row*FIN+cc]*inv_img),-128.f),127.f) : 0.f;
      xqb[i]=f2bf(q);
    } else if(i<T1){
      int j=i-T0; int o=j>>5, cc=j&31;
      float q = cc<FIN ? fminf(fmaxf(rintf(W1[o*FIN+cc]/s_w1),-4.f),3.f) : 0.f;
      w1b[j]=f2bf(q);
    } else if(i<T2){
      int j=i-T1; int c=j>>4, k=j&15;
      char q=0;
      if(k<KW) q=(char)(int)fminf(fmaxf(rintf(Wc[c*KW+k]/s_wc),-4.f),3.f);
      wcpk[j]=q;
    } else {
      int j=i-T2;                 // wfb[n][c*28+l]
      int n=j/10752, r=j-n*10752;
      int c=r/28, l=r-c*28;
      wfb[j]=(char)(int)fminf(fmaxf(rintf(Wf[n*10752+l*MD+c]/s_wf),-4.f),3.f);
    }
  }
}

// Fused block = 3 samples (84 real rows, staged as 6x16 with clamp), 1366 blocks.
// MODE 0: lin minmax. MODE 1: lin codes -> conv minmax. MODE 2: full -> logits.
#define CWS 23          // Cw row stride (ints): 21 data + 2 pad, coprime with 32
#define DWS 2692        // Dw sample stride in INTS (2688 data + 4 pad) = 10768 B
template<int MODE>
__global__ __launch_bounds__(512)
void k_fused(const unsigned short* __restrict__ xqb,const unsigned short* __restrict__ w1b,
             const float* __restrict__ b1,const float* __restrict__ scf,
             const char* __restrict__ lut1g,const char* __restrict__ lut2g,
             const char* __restrict__ wcpk,const float* __restrict__ bc,
             const char* __restrict__ wfb,const float* __restrict__ bfv,
             float2* __restrict__ ptmm,float* __restrict__ lg,
             float* __restrict__ ptl){
  __shared__ int ldsI[MD*CWS];         // W1 stage(6144) -> Cw[384][23] -> Dw 3xDWS
  __shared__ int psumN[8][10][4];
  int t=threadIdx.x, wid=t>>6, lane=t&63, l4=lane>>4, l15=lane&15;
  {
    const int* src=(const int*)w1b;
    for(int i=t;i<6144;i+=512) ldsI[i]=src[i];
  }
  __syncthreads();
  unsigned short* Wlds=(unsigned short*)ldsI;
  bf16x8 bfr[3]; float b1v[3];
  #pragma unroll
  for(int ni=0;ni<3;ni++){
    int o=(wid*3+ni)*16+l15;
    bfr[ni]=*(const bf16x8*)&Wlds[o*32+l4*8];
    b1v[ni]=b1[o];
  }
  bf16x8 af[6];
  int r0=blockIdx.x*84;
  #pragma unroll
  for(int mt=0;mt<6;mt++){
    int rr_=r0+mt*16+l15; rr_=min(rr_,NROWS-1);   // clamp: duplicates of real rows
    af[mt]=*(const bf16x8*)&xqb[(size_t)rr_*32+l4*8];
  }
  int vs=BATCH-blockIdx.x*SAMP;        // valid samples this block (>=3 except last)
  float sg=scf[0]*scf[1];
  float sgi=sg, b1s[3]={0.f,0.f,0.f};
  int lutA_w=0,lutB_w=0;
  float ck1=1.f,inv_cv=1.f,sfac=1.f,gsc=1.f;
  if constexpr(MODE>=1){
    float inv_lin=1.f/scf[4];
    sgi=sg*inv_lin;
    #pragma unroll
    for(int ni=0;ni<3;ni++) b1s[ni]=fmaf(b1v[ni],inv_lin,128.f);
    lutA_w=((const int*)lut1g)[lane];
    sfac=scf[5]*scf[2];                 // s_o1 * s_wc
  }
  if constexpr(MODE==2){
    inv_cv=1.f/scf[6];
    ck1=sfac*inv_cv;
    gsc=scf[3]*scf[7];                  // s_wf * s_o2
    lutB_w=((const int*)lut2g)[lane];
  }
  if constexpr(MODE>=1) __syncthreads();   // Wlds frag reads done before Cw overwrite

  f32x4 zero={0.f,0.f,0.f,0.f};
  float mnn[3]={1e30f,1e30f,1e30f},mxx[3]={-1e30f,-1e30f,-1e30f};
  #pragma unroll
  for(int ni=0;ni<3;ni++){
    int o=(wid*3+ni)*16+l15;
    #pragma unroll
    for(int mt=0;mt<6;mt++){
      f32x4 acc=__builtin_amdgcn_mfma_f32_16x16x32_bf16(af[mt],bfr[ni],zero,0,0,0);
      if constexpr(MODE==0){
        #pragma unroll
        for(int r=0;r<4;r++){
          mnn[ni]=fminf(mnn[ni],acc[r]); mxx[ni]=fmaxf(mxx[ni],acc[r]);
        }
      } else {
        unsigned w=0;
        #pragma unroll
        for(int r=0;r<4;r++){
          float x=fmaf(acc[r],sgi,b1s[ni]);   // quant domain, biased +128
          int iw=(int)__builtin_amdgcn_fmed3f(rintf(x),0.f,255.f);
          w|=lut_bperm(iw,lutA_w)<<(8*r);
        }
        int idx=mt*4+l4;                       // word index = s*7 + l/4, valid < 21
        if(idx<21) ldsI[o*CWS+idx]=(int)w;
      }
    }
  }
  if constexpr(MODE==0){
    float mn=1e30f,mx=-1e30f;
    #pragma unroll
    for(int ni=0;ni<3;ni++){
      mn=fminf(mn,fmaf(mnn[ni],sg,b1v[ni]));
      mx=fmaxf(mx,fmaf(mxx[ni],sg,b1v[ni]));
    }
    blkStoreMM(mn,mx,&ptmm[blockIdx.x]);
    return;
  }
  __syncthreads();

  // depthwise conv: 1152 rows (s,c), up to 3 per thread
  int oww[3][7];
  float mnc=1e30f,mxc=-1e30f;
  #pragma unroll
  for(int rr=0;rr<3;rr++){
    int j=t+rr*512;
    if(j<SAMP*MD){
      int s=j/MD, c=j-s*MD;
      i32x4 wq=*(const i32x4*)(wcpk+(size_t)c*16);
      float cbias=bc[c];
      float cq2=0.f;
      if constexpr(MODE==2) cq2=fmaf(cbias,inv_cv,128.f);
      int ext[11];
      ext[0]=0; ext[1]=0; ext[9]=0; ext[10]=0;
      #pragma unroll
      for(int i=0;i<7;i++) ext[2+i]=ldsI[c*CWS+s*7+i];
      int imn=0x7FFFFFFF,imx=0x80000000;
      #pragma unroll
      for(int l=0;l<LSEQ;l++){
        const int eb=l+1, bi=eb>>2, sh=eb&3;
        int A0,A1,A2,A3;
        if(sh==0){A0=ext[bi];A1=ext[bi+1];A2=ext[bi+2];A3=ext[bi+3];}
        else{
          A0=ALIGNB(ext[bi+1],ext[bi],sh);
          A1=ALIGNB(ext[bi+2],ext[bi+1],sh);
          A2=ALIGNB(ext[bi+3],ext[bi+2],sh);
          A3=ALIGNB(ext[bi+4],ext[bi+3],sh);
        }
        int idot=SDOT4(A0,wq[0],SDOT4(A1,wq[1],SDOT4(A2,wq[2],SDOT4(A3,wq[3],0))));
        if constexpr(MODE==1){
          imn=min(imn,idot); imx=max(imx,idot);
        } else {
          float x=fmaf((float)idot,ck1,cq2);
          int iw=(int)__builtin_amdgcn_fmed3f(rintf(x),0.f,255.f);
          unsigned q2=lut_bperm(iw,lutB_w);
          if((l&3)==0) oww[rr][l>>2]=(int)q2;
          else oww[rr][l>>2]|=(int)(q2<<(8*(l&3)));
        }
      }
      if constexpr(MODE==1){
        if(s<vs){                          // exclude fake samples (last block)
          mnc=fminf(mnc,fmaf((float)imn,sfac,cbias));
          mxc=fmaxf(mxc,fmaf((float)imx,sfac,cbias));
        }
      }
    }
  }
  if constexpr(MODE==1){
    blkStoreMM(mnc,mxc,&ptmm[blockIdx.x]);
    return;
  }

  // MODE 2: rewrite conv codes sample-major Dw[s*DWS + c*7 + i]
  __syncthreads();
  #pragma unroll
  for(int rr=0;rr<3;rr++){
    int j=t+rr*512;
    if(j<SAMP*MD){
      int s=j/MD, c=j-s*MD;
      #pragma unroll
      for(int i=0;i<7;i++) ldsI[s*DWS+c*7+i]=oww[rr][i];
    }
  }
  __syncthreads();

  // in-block gemm2 via i8 MFMA. K = 10752 B = 168 k-blocks of 64; 21/wave.
  // A rows = samples (clamped to <=2, in-bounds), B cols = classes (>=10 pad).
  {
    i32x4 acc={0,0,0,0};
    const char* ldsB=(const char*)ldsI;
    int ar=l15&3; if(ar>2) ar=2;
    for(int kb=wid;kb<168;kb+=8){
      i32x4 a=*(const i32x4*)(ldsB+(size_t)ar*(DWS*4)+kb*64+l4*16);
      i32x4 b=*(const i32x4*)(wfb+(size_t)l15*10752+kb*64+l4*16);
      acc=__builtin_amdgcn_mfma_i32_16x16x64_i8(a,b,acc,0,0,0);
    }
    if(l4==0&&l15<10){
      #pragma unroll
      for(int r=0;r<4;r++) psumN[wid][l15][r]=acc[r];
    }
  }
  __syncthreads();
  float m=0.f;
  if(t<30){
    int s=t/10, o=t-s*10;
    if(blockIdx.x*SAMP+s<BATCH){
      int sum=0;
      #pragma unroll
      for(int w=0;w<8;w++) sum+=psumN[w][o][s];
      float v=fmaf((float)sum,gsc,bfv[o]);
      lg[(size_t)(blockIdx.x*SAMP+s)*10+o]=v;
      m=fabsf(v);
    }
  }
  if(t<64){
    #pragma unroll
    for(int off=32;off;off>>=1) m=fmaxf(m,__shfl_xor(m,off,64));
    if(t==0) ptl[blockIdx.x]=m;
  }
}

__global__ __launch_bounds__(256)
void k_final(const float* __restrict__ lg,const float* __restrict__ ptl,
             float* __restrict__ out){
  int t=threadIdx.x;
  float m=0.f;
  for(int i=t;i<NB;i+=256) m=fmaxf(m,ptl[i]);
  #pragma unroll
  for(int off=32;off;off>>=1) m=fmaxf(m,__shfl_xor(m,off,64));
  __shared__ float sm[4];
  __shared__ float sv;
  int wid=t>>6;
  if((t&63)==0) sm[wid]=m;
  __syncthreads();
  if(t==0){
    for(int k=1;k<4;k++) m=fmaxf(m,sm[k]);
    sv=fmaxf(m/127.f,1e-8f);
  }
  __syncthreads();
  float s=sv;
  int i=blockIdx.x*256+t;
  out[i]=fminf(fmaxf(rintf(lg[i]/s),-128.f),127.f)*s;
}

extern "C" void kernel_launch(void* const* d_in, const int* in_sizes, int n_in,
                              void* d_out, int out_size, void* d_ws, size_t ws_size,
                              hipStream_t stream){
  const float* img=(const float*)d_in[0];
  const float* W1 =(const float*)d_in[1];
  const float* b1 =(const float*)d_in[2];
  const float* Wc =(const float*)d_in[3];
  const float* bc =(const float*)d_in[4];
  const float* Wf =(const float*)d_in[5];
  const float* bf =(const float*)d_in[6];
  float* out=(float*)d_out;
  char* wsb=(char*)d_ws;
  float* scf=(float*)(wsb+B_SCF);
  float4* pt0=(float4*)(wsb+B_PT0);
  float2* pt1=(float2*)(wsb+B_PT1);
  float2* pt2=(float2*)(wsb+B_PT2);
  float* ptl=(float*)(wsb+B_PTL);
  float* lg=(float*)(wsb+B_LG);
  const unsigned short* xqb=(const unsigned short*)(wsb+B_XQB);
  const unsigned short* w1b=(const unsigned short*)(wsb+B_W1B);
  const char* wcpk=wsb+B_WCQ;
  const char* wfb=wsb+B_WFB;

  k_maxabs_in<<<2048,256,0,stream>>>(img,W1,Wc,Wf,pt0);
  k_red0<<<1,256,0,stream>>>(pt0,scf);
  k_prep<<<4096,256,0,stream>>>(img,W1,Wc,Wf,scf,wsb);
  k_fused<0><<<NB,512,0,stream>>>(xqb,w1b,b1,scf,nullptr,nullptr,wcpk,bc,wfb,bf,pt1,nullptr,nullptr);
  k_redmm<<<1,256,0,stream>>>(pt1,NB,scf,4,5,wsb+B_LUT1);
  k_fused<1><<<NB,512,0,stream>>>(xqb,w1b,b1,scf,wsb+B_LUT1,nullptr,wcpk,bc,wfb,bf,pt2,nullptr,nullptr);
  k_redmm<<<1,256,0,stream>>>(pt2,NB,scf,6,7,wsb+B_LUT2);
  k_fused<2><<<NB,512,0,stream>>>(xqb,w1b,b1,scf,wsb+B_LUT1,wsb+B_LUT2,wcpk,bc,wfb,bf,nullptr,lg,ptl);
  k_final<<<160,256,0,stream>>>(lg,ptl,out);
}

// Round 13
// 104.786 us; speedup vs baseline: 1.2501x; 1.2501x over previous
//
#include <hip/hip_runtime.h>

#define BATCH 4096
#define MD 384
#define KW 15
#define LSEQ 28
#define FIN 28
#define NX (BATCH*LSEQ*FIN)
#define NROWS (BATCH*LSEQ)

// scf slots: 0 s_img, 1 s_w1, 2 s_wc, 3 s_wf, 4 s_lin, 5 s_o1, 6 s_cv, 7 s_o2
// workspace layout (byte offsets, 16B-aligned)
#define B_SCF  0
#define B_LUT1 256
#define B_LUT2 512
#define B_PT0  1024      // 2048 float4
#define B_PT1  33792     // 1024 float2
#define B_PT2  50176     // 1024 float2
#define B_PTL  66560     // 1024 float
#define B_W1B  74752     // MD*32 bf16 = 24576
#define B_WCQ  99328     // MD*16 i8 = 6144
#define B_WFB  105472    // 16*10752 i8 = 172032 (rows 10..15 pad)
#define B_LG   277504    // 40960 float
#define B_XQB  441344    // NROWS*32 bf16 = 7340032 -> 7781376
#define B_CWG  7781376   // 1024 blocks * 10752 ints = 44040192 B

typedef __bf16 bf16x8 __attribute__((ext_vector_type(8)));
typedef float f32x4 __attribute__((ext_vector_type(4)));
typedef int i32x4 __attribute__((ext_vector_type(4)));

#if __has_builtin(__builtin_amdgcn_sdot4)
#define SDOT4(a,b,c) __builtin_amdgcn_sdot4((a),(b),(c),false)
#else
__device__ __forceinline__ int SDOT4(int a,int b,int c){
  c += ((a<<24)>>24)*((b<<24)>>24);
  c += ((a<<16)>>24)*((b<<16)>>24);
  c += ((a<<8)>>24)*((b<<8)>>24);
  c += (a>>24)*(b>>24);
  return c;
}
#endif

#if __has_builtin(__builtin_amdgcn_alignbyte)
#define ALIGNB(hi,lo,s) __builtin_amdgcn_alignbyte((hi),(lo),(s))
#else
#define ALIGNB(hi,lo,s) ((int)(((unsigned)(lo)>>(8*(s)))|((unsigned)(hi)<<(32-8*(s)))))
#endif

__device__ __forceinline__ unsigned short f2bf(float f){
  return (unsigned short)(__float_as_uint(f)>>16);   // exact for small ints
}
__device__ __forceinline__ unsigned lut_bperm(int iw,int lutw){
  int res=__builtin_amdgcn_ds_bpermute(iw,lutw);    // lane = iw>>2
  return ((unsigned)res>>(8*(iw&3)))&0xFFu;
}

__device__ __forceinline__ void blkStore4(float m0,float m1,float m2,float m3,float4* dst){
  #pragma unroll
  for(int off=32;off;off>>=1){
    m0=fmaxf(m0,__shfl_xor(m0,off,64));
    m1=fmaxf(m1,__shfl_xor(m1,off,64));
    m2=fmaxf(m2,__shfl_xor(m2,off,64));
    m3=fmaxf(m3,__shfl_xor(m3,off,64));
  }
  __shared__ float sm[4][4];
  int wid=threadIdx.x>>6;
  if((threadIdx.x&63)==0){sm[wid][0]=m0;sm[wid][1]=m1;sm[wid][2]=m2;sm[wid][3]=m3;}
  __syncthreads();
  if(threadIdx.x==0){
    for(int i=1;i<4;i++){
      m0=fmaxf(m0,sm[i][0]);m1=fmaxf(m1,sm[i][1]);
      m2=fmaxf(m2,sm[i][2]);m3=fmaxf(m3,sm[i][3]);
    }
    *dst=make_float4(m0,m1,m2,m3);
  }
}

__device__ __forceinline__ void blkStoreMM(float mn,float mx,float2* dst){
  #pragma unroll
  for(int off=32;off;off>>=1){
    mn=fminf(mn,__shfl_xor(mn,off,64));
    mx=fmaxf(mx,__shfl_xor(mx,off,64));
  }
  __shared__ float smn[8],smx[8];
  int wid=threadIdx.x>>6, nw=blockDim.x>>6;
  if((threadIdx.x&63)==0){smn[wid]=mn;smx[wid]=mx;}
  __syncthreads();
  if(threadIdx.x==0){
    for(int i=1;i<nw;i++){mn=fminf(mn,smn[i]);mx=fmaxf(mx,smx[i]);}
    *dst=make_float2(mn,mx);
  }
}

// ---------- kernels ----------
__global__ __launch_bounds__(256)
void k_maxabs_in(const float* __restrict__ img,const float* __restrict__ W1,
                 const float* __restrict__ Wc,const float* __restrict__ Wf,
                 float4* __restrict__ pt0){
  float m0=0.f,m1=0.f,m2=0.f,m3=0.f;
  const int N4=NX/4;
  const int NW1=MD*FIN, NWC=MD*KW, NWF=10*MD*LSEQ;
  const int total=N4+NW1+NWC+NWF;
  const float4* img4=(const float4*)img;
  for(int i=blockIdx.x*blockDim.x+threadIdx.x;i<total;i+=gridDim.x*blockDim.x){
    if(i<N4){
      float4 v=img4[i];
      m0=fmaxf(m0,fmaxf(fmaxf(fabsf(v.x),fabsf(v.y)),fmaxf(fabsf(v.z),fabsf(v.w))));
    }
    else if(i<N4+NW1) m1=fmaxf(m1,fabsf(W1[i-N4]));
    else if(i<N4+NW1+NWC) m2=fmaxf(m2,fabsf(Wc[i-N4-NW1]));
    else m3=fmaxf(m3,fabsf(Wf[i-N4-NW1-NWC]));
  }
  blkStore4(m0,m1,m2,m3,&pt0[blockIdx.x]);
}

__global__ __launch_bounds__(256)
void k_red0(const float4* __restrict__ pt,float* __restrict__ scf){
  int t=threadIdx.x;
  float m0=0.f,m1=0.f,m2=0.f,m3=0.f;
  for(int i=t;i<2048;i+=256){
    float4 v=pt[i];
    m0=fmaxf(m0,v.x);m1=fmaxf(m1,v.y);m2=fmaxf(m2,v.z);m3=fmaxf(m3,v.w);
  }
  #pragma unroll
  for(int off=32;off;off>>=1){
    m0=fmaxf(m0,__shfl_xor(m0,off,64));
    m1=fmaxf(m1,__shfl_xor(m1,off,64));
    m2=fmaxf(m2,__shfl_xor(m2,off,64));
    m3=fmaxf(m3,__shfl_xor(m3,off,64));
  }
  __shared__ float sm[4][4];
  int wid=t>>6;
  if((t&63)==0){sm[wid][0]=m0;sm[wid][1]=m1;sm[wid][2]=m2;sm[wid][3]=m3;}
  __syncthreads();
  if(t==0){
    for(int i=1;i<4;i++){
      m0=fmaxf(m0,sm[i][0]);m1=fmaxf(m1,sm[i][1]);
      m2=fmaxf(m2,sm[i][2]);m3=fmaxf(m3,sm[i][3]);
    }
    scf[0]=fmaxf(m0/127.f,1e-8f);
    scf[1]=fmaxf(m1/3.f,1e-8f);
    scf[2]=fmaxf(m2/3.f,1e-8f);
    scf[3]=fmaxf(m3/3.f,1e-8f);
  }
}

__global__ __launch_bounds__(256)
void k_redmm(const float2* __restrict__ pt,int n,float* __restrict__ scf,
             int preIdx,int outIdx,char* __restrict__ lutg){
  int t=threadIdx.x;
  float mn=1e30f,mx=-1e30f;
  for(int i=t;i<n;i+=256){
    float2 v=pt[i];
    mn=fminf(mn,v.x); mx=fmaxf(mx,v.y);
  }
  #pragma unroll
  for(int off=32;off;off>>=1){
    mn=fminf(mn,__shfl_xor(mn,off,64));
    mx=fmaxf(mx,__shfl_xor(mx,off,64));
  }
  __shared__ float smn[4],smx[4];
  __shared__ float bs,bso;
  int wid=t>>6;
  if((t&63)==0){smn[wid]=mn;smx[wid]=mx;}
  __syncthreads();
  if(t==0){
    for(int i=1;i<4;i++){mn=fminf(mn,smn[i]);mx=fmaxf(mx,smx[i]);}
    float ma=fmaxf(fabsf(mn),fabsf(mx));
    float s=fmaxf(ma/127.f,1e-8f);
    float a1=fabsf(fminf(fmaxf(rintf(mn/s),-128.f),127.f)*s);
    float a2=fabsf(fminf(fmaxf(rintf(mx/s),-128.f),127.f)*s);
    float so=fmaxf(tanhf(fmaxf(a1,a2))/127.f,1e-8f);
    scf[preIdx]=s; scf[outIdx]=so;
    bs=s; bso=so;
  }
  __syncthreads();
  float d=(float)(t-128)*bs;
  lutg[t]=(char)(int)fminf(fmaxf(rintf(tanhf(d)/bso),-128.f),127.f);
}

// quantize inputs into code tensors
__global__ __launch_bounds__(256)
void k_prep(const float* __restrict__ img,const float* __restrict__ W1,
            const float* __restrict__ Wc,const float* __restrict__ Wf,
            const float* __restrict__ scf,char* __restrict__ wsb){
  float s_img=scf[0], s_w1=scf[1], s_wc=scf[2], s_wf=scf[3];
  float inv_img=1.f/s_img;
  unsigned short* xqb=(unsigned short*)(wsb+B_XQB);
  unsigned short* w1b=(unsigned short*)(wsb+B_W1B);
  char* wcpk=wsb+B_WCQ;
  char* wfb=wsb+B_WFB;
  const int T0=NROWS*32;
  const int T1=T0+MD*32;
  const int T2=T1+MD*16;
  const int T3=T2+10*10752;
  for(int i=blockIdx.x*blockDim.x+threadIdx.x;i<T3;i+=gridDim.x*blockDim.x){
    if(i<T0){
      int row=i>>5, cc=i&31;
      float q = cc<FIN ? fminf(fmaxf(rintf(img[row*FIN+cc]*inv_img),-128.f),127.f) : 0.f;
      xqb[i]=f2bf(q);
    } else if(i<T1){
      int j=i-T0; int o=j>>5, cc=j&31;
      float q = cc<FIN ? fminf(fmaxf(rintf(W1[o*FIN+cc]/s_w1),-4.f),3.f) : 0.f;
      w1b[j]=f2bf(q);
    } else if(i<T2){
      int j=i-T1; int c=j>>4, k=j&15;
      char q=0;
      if(k<KW) q=(char)(int)fminf(fmaxf(rintf(Wc[c*KW+k]/s_wc),-4.f),3.f);
      wcpk[j]=q;
    } else {
      int j=i-T2;                 // wfb[n][c*28+l]
      int n=j/10752, r=j-n*10752;
      int c=r/28, l=r-c*28;
      wfb[j]=(char)(int)fminf(fmaxf(rintf(Wf[n*10752+l*MD+c]/s_wf),-4.f),3.f);
    }
  }
}

// Fused block = 4 samples (112 rows x 384 o), 1024 blocks, 512 threads.
// MODE 0: lin minmax -> pt1. MODE 1: lin codes (dumped to cwg) -> conv minmax -> pt2.
// MODE 2: load cwg -> conv codes -> in-block i8-MFMA gemm2 -> logits + max partial.
#define CWS 29          // padded Cw row stride (ints), coprime with 32
#define DWS 2692        // Dw sample stride in INTS (2688 data + 4 pad) = 10768 B
template<int MODE>
__global__ __launch_bounds__(512)
void k_fused(const unsigned short* __restrict__ xqb,const unsigned short* __restrict__ w1b,
             const float* __restrict__ b1,const float* __restrict__ scf,
             const char* __restrict__ lut1g,const char* __restrict__ lut2g,
             const char* __restrict__ wcpk,const float* __restrict__ bc,
             const char* __restrict__ wfb,const float* __restrict__ bfv,
             int* __restrict__ cwg,
             float2* __restrict__ ptmm,float* __restrict__ lg,
             float* __restrict__ ptl){
  __shared__ int ldsI[MD*CWS];         // W1 stage -> Cw[384][29] -> Dw 4xDWS overlay
  __shared__ int psumN[8][10][4];
  int t=threadIdx.x, wid=t>>6, lane=t&63, l4=lane>>4, l15=lane&15;

  bf16x8 bfr[3]; float b1v[3]; bf16x8 af[7];
  if constexpr(MODE<2){
    const int* src=(const int*)w1b;
    for(int i=t;i<6144;i+=512) ldsI[i]=src[i];
    __syncthreads();
    unsigned short* Wlds=(unsigned short*)ldsI;
    #pragma unroll
    for(int ni=0;ni<3;ni++){
      int o=(wid*3+ni)*16+l15;
      bfr[ni]=*(const bf16x8*)&Wlds[o*32+l4*8];
      b1v[ni]=b1[o];
    }
    int r0=blockIdx.x*112;
    #pragma unroll
    for(int mt=0;mt<7;mt++)
      af[mt]=*(const bf16x8*)&xqb[(size_t)(r0+mt*16+l15)*32+l4*8];
  } else {
    // load lin codes from cwg into Cw[384][29] layout
    const int4* src=(const int4*)(cwg+(size_t)blockIdx.x*10752);
    for(int jj=t;jj<2688;jj+=512){
      int4 v=src[jj];
      int j=jj*4, o=j/28, idx=j-o*28, base=o*CWS+idx;
      ldsI[base]=v.x; ldsI[base+1]=v.y; ldsI[base+2]=v.z; ldsI[base+3]=v.w;
    }
  }

  float sg=scf[0]*scf[1];
  float sgi=sg, b1s[3]={0.f,0.f,0.f};
  int lutA_w=0,lutB_w=0;
  float ck1=1.f,inv_cv=1.f,sfac=1.f,gsc=1.f;
  if constexpr(MODE>=1){
    sfac=scf[5]*scf[2];                 // s_o1 * s_wc
  }
  if constexpr(MODE==1){
    float inv_lin=1.f/scf[4];
    sgi=sg*inv_lin;
    #pragma unroll
    for(int ni=0;ni<3;ni++) b1s[ni]=fmaf(b1v[ni],inv_lin,128.f);
    lutA_w=((const int*)lut1g)[lane];
  }
  if constexpr(MODE==2){
    inv_cv=1.f/scf[6];
    ck1=sfac*inv_cv;                    // idot -> quant domain
    gsc=scf[3]*scf[7];                  // s_wf * s_o2
    lutB_w=((const int*)lut2g)[lane];
  }
  if constexpr(MODE>=1) __syncthreads();   // MODE1: Wlds reads done; MODE2: cwg load done

  if constexpr(MODE<2){
    f32x4 zero={0.f,0.f,0.f,0.f};
    float mnn[3]={1e30f,1e30f,1e30f},mxx[3]={-1e30f,-1e30f,-1e30f};
    #pragma unroll
    for(int ni=0;ni<3;ni++){
      int o=(wid*3+ni)*16+l15;
      #pragma unroll
      for(int mt=0;mt<7;mt++){
        f32x4 acc=__builtin_amdgcn_mfma_f32_16x16x32_bf16(af[mt],bfr[ni],zero,0,0,0);
        if constexpr(MODE==0){
          #pragma unroll
          for(int r=0;r<4;r++){
            mnn[ni]=fminf(mnn[ni],acc[r]); mxx[ni]=fmaxf(mxx[ni],acc[r]);
          }
        } else {
          unsigned w=0;
          #pragma unroll
          for(int r=0;r<4;r++){
            float x=fmaf(acc[r],sgi,b1s[ni]);   // quant domain, biased +128
            int iw=(int)__builtin_amdgcn_fmed3f(rintf(x),0.f,255.f);
            w|=lut_bperm(iw,lutA_w)<<(8*r);
          }
          ldsI[o*CWS+mt*4+l4]=(int)w;
        }
      }
    }
    if constexpr(MODE==0){
      float mn=1e30f,mx=-1e30f;
      #pragma unroll
      for(int ni=0;ni<3;ni++){
        mn=fminf(mn,fmaf(mnn[ni],sg,b1v[ni]));
        mx=fmaxf(mx,fmaf(mxx[ni],sg,b1v[ni]));
      }
      blkStoreMM(mn,mx,&ptmm[blockIdx.x]);
      return;
    }
    __syncthreads();                     // Cw complete
    // MODE 1: dump Cw codes to global (coalesced int4); read-only on ldsI
    {
      int4* dst=(int4*)(cwg+(size_t)blockIdx.x*10752);
      for(int jj=t;jj<2688;jj+=512){
        int j=jj*4, o=j/28, idx=j-o*28, base=o*CWS+idx;
        int4 v; v.x=ldsI[base]; v.y=ldsI[base+1]; v.z=ldsI[base+2]; v.w=ldsI[base+3];
        dst[jj]=v;
      }
    }
  }

  // depthwise conv: 1536 rows (s,c), 3 per thread
  int oww[3][7];
  float mnc=1e30f,mxc=-1e30f;
  #pragma unroll
  for(int rr=0;rr<3;rr++){
    int j=t+rr*512;
    int s=j/384, c=j-s*384;
    i32x4 wq=*(const i32x4*)(wcpk+(size_t)c*16);
    float cbias=bc[c];
    float cq2=0.f;
    if constexpr(MODE==2) cq2=fmaf(cbias,inv_cv,128.f);
    int ext[11];
    ext[0]=0; ext[1]=0; ext[9]=0; ext[10]=0;
    #pragma unroll
    for(int i=0;i<7;i++) ext[2+i]=ldsI[c*CWS+s*7+i];
    int imn=0x7FFFFFFF,imx=0x80000000;
    #pragma unroll
    for(int l=0;l<LSEQ;l++){
      const int eb=l+1, bi=eb>>2, sh=eb&3;
      int A0,A1,A2,A3;
      if(sh==0){A0=ext[bi];A1=ext[bi+1];A2=ext[bi+2];A3=ext[bi+3];}
      else{
        A0=ALIGNB(ext[bi+1],ext[bi],sh);
        A1=ALIGNB(ext[bi+2],ext[bi+1],sh);
        A2=ALIGNB(ext[bi+3],ext[bi+2],sh);
        A3=ALIGNB(ext[bi+4],ext[bi+3],sh);
      }
      int idot=SDOT4(A0,wq[0],SDOT4(A1,wq[1],SDOT4(A2,wq[2],SDOT4(A3,wq[3],0))));
      if constexpr(MODE==1){
        imn=min(imn,idot); imx=max(imx,idot);
      } else {
        float x=fmaf((float)idot,ck1,cq2);
        int iw=(int)__builtin_amdgcn_fmed3f(rintf(x),0.f,255.f);
        unsigned q2=lut_bperm(iw,lutB_w);
        if((l&3)==0) oww[rr][l>>2]=(int)q2;
        else oww[rr][l>>2]|=(int)(q2<<(8*(l&3)));
      }
    }
    if constexpr(MODE==1){
      mnc=fminf(mnc,fmaf((float)imn,sfac,cbias));
      mxc=fmaxf(mxc,fmaf((float)imx,sfac,cbias));
    }
  }
  if constexpr(MODE==1){
    blkStoreMM(mnc,mxc,&ptmm[blockIdx.x]);
    return;
  }

  // MODE 2: rewrite conv codes sample-major Dw[s*DWS + c*7 + i] (10768-B stride)
  __syncthreads();
  #pragma unroll
  for(int rr=0;rr<3;rr++){
    int j=t+rr*512;
    int s=j/384, c=j-s*384;
    #pragma unroll
    for(int i=0;i<7;i++) ldsI[s*DWS+c*7+i]=oww[rr][i];
  }
  __syncthreads();

  // in-block gemm2 via i8 MFMA. K = 10752 B = 168 k-blocks of 64; 21/wave.
  {
    i32x4 acc={0,0,0,0};
    const char* ldsB=(const char*)ldsI;
    for(int kb=wid;kb<168;kb+=8){
      i32x4 a=*(const i32x4*)(ldsB+(size_t)(l15&3)*(DWS*4)+kb*64+l4*16);
      i32x4 b=*(const i32x4*)(wfb+(size_t)l15*10752+kb*64+l4*16);
      acc=__builtin_amdgcn_mfma_i32_16x16x64_i8(a,b,acc,0,0,0);
    }
    if(l4==0&&l15<10){
      #pragma unroll
      for(int r=0;r<4;r++) psumN[wid][l15][r]=acc[r];
    }
  }
  __syncthreads();
  float m=0.f;
  if(t<40){
    int s=t/10, o=t-s*10;
    int sum=0;
    #pragma unroll
    for(int w=0;w<8;w++) sum+=psumN[w][o][s];
    float v=fmaf((float)sum,gsc,bfv[o]);
    lg[(blockIdx.x*4+s)*10+o]=v;
    m=fabsf(v);
  }
  if(t<64){
    #pragma unroll
    for(int off=32;off;off>>=1) m=fmaxf(m,__shfl_xor(m,off,64));
    if(t==0) ptl[blockIdx.x]=m;
  }
}

__global__ __launch_bounds__(256)
void k_final(const float* __restrict__ lg,const float* __restrict__ ptl,
             float* __restrict__ out){
  int t=threadIdx.x;
  float m=0.f;
  for(int i=t;i<1024;i+=256) m=fmaxf(m,ptl[i]);
  #pragma unroll
  for(int off=32;off;off>>=1) m=fmaxf(m,__shfl_xor(m,off,64));
  __shared__ float sm[4];
  __shared__ float sv;
  int wid=t>>6;
  if((t&63)==0) sm[wid]=m;
  __syncthreads();
  if(t==0){
    for(int k=1;k<4;k++) m=fmaxf(m,sm[k]);
    sv=fmaxf(m/127.f,1e-8f);
  }
  __syncthreads();
  float s=sv;
  int i=blockIdx.x*256+t;
  out[i]=fminf(fmaxf(rintf(lg[i]/s),-128.f),127.f)*s;
}

extern "C" void kernel_launch(void* const* d_in, const int* in_sizes, int n_in,
                              void* d_out, int out_size, void* d_ws, size_t ws_size,
                              hipStream_t stream){
  const float* img=(const float*)d_in[0];
  const float* W1 =(const float*)d_in[1];
  const float* b1 =(const float*)d_in[2];
  const float* Wc =(const float*)d_in[3];
  const float* bc =(const float*)d_in[4];
  const float* Wf =(const float*)d_in[5];
  const float* bf =(const float*)d_in[6];
  float* out=(float*)d_out;
  char* wsb=(char*)d_ws;
  float* scf=(float*)(wsb+B_SCF);
  float4* pt0=(float4*)(wsb+B_PT0);
  float2* pt1=(float2*)(wsb+B_PT1);
  float2* pt2=(float2*)(wsb+B_PT2);
  float* ptl=(float*)(wsb+B_PTL);
  float* lg=(float*)(wsb+B_LG);
  int* cwg=(int*)(wsb+B_CWG);
  const unsigned short* xqb=(const unsigned short*)(wsb+B_XQB);
  const unsigned short* w1b=(const unsigned short*)(wsb+B_W1B);
  const char* wcpk=wsb+B_WCQ;
  const char* wfb=wsb+B_WFB;

  k_maxabs_in<<<2048,256,0,stream>>>(img,W1,Wc,Wf,pt0);
  k_red0<<<1,256,0,stream>>>(pt0,scf);
  k_prep<<<4096,256,0,stream>>>(img,W1,Wc,Wf,scf,wsb);
  k_fused<0><<<1024,512,0,stream>>>(xqb,w1b,b1,scf,nullptr,nullptr,wcpk,bc,wfb,bf,cwg,pt1,nullptr,nullptr);
  k_redmm<<<1,256,0,stream>>>(pt1,1024,scf,4,5,wsb+B_LUT1);
  k_fused<1><<<1024,512,0,stream>>>(xqb,w1b,b1,scf,wsb+B_LUT1,nullptr,wcpk,bc,wfb,bf,cwg,pt2,nullptr,nullptr);
  k_redmm<<<1,256,0,stream>>>(pt2,1024,scf,6,7,wsb+B_LUT2);
  k_fused<2><<<1024,512,0,stream>>>(xqb,w1b,b1,scf,wsb+B_LUT1,wsb+B_LUT2,wcpk,bc,wfb,bf,cwg,nullptr,lg,ptl);
  k_final<<<160,256,0,stream>>>(lg,ptl,out);
}